// Round 3
// baseline (159.683 us; speedup 1.0000x reference)
//
#include <hip/hip_runtime.h>
#include <stdint.h>

// N = D*H*W = 8*32*32 voxels; C = 64 channels.
constexpr int N = 8192;
// softmax scale (1/sqrt(64)) * log2(e), folded into Q (attn works in exp2 domain).
constexpr float QSCALE = 0.18033688011112042f;
constexpr int SPLIT = 4;   // chunk-pairs across blockIdx.y; in-block split 2 -> 8 chunks

typedef __attribute__((ext_vector_type(4))) float f32x4;
typedef __attribute__((ext_vector_type(4))) unsigned int u32x4;
typedef __attribute__((ext_vector_type(2))) unsigned int u32x2;
typedef __attribute__((ext_vector_type(4))) unsigned short u16x4;

__device__ inline unsigned short f2bf(float f) {
  unsigned u = __builtin_bit_cast(unsigned, f);
  u += 0x7FFFu + ((u >> 16) & 1u);
  return (unsigned short)(u >> 16);
}
__device__ inline float bf2f(unsigned short u) {
  return __builtin_bit_cast(float, (unsigned)u << 16);
}
// pack two f32 -> two bf16 in one u32 (low=a, high=b); no builtin on gfx950 -> asm
__device__ inline unsigned cvtpk(float a, float b) {
  unsigned r;
  asm("v_cvt_pk_bf16_f32 %0, %1, %2" : "=v"(r) : "v"(a), "v"(b));
  return r;
}

// D = A*B + D, 16x16x32 bf16. A: lane holds A[lane&15][8*(lane>>4)+e];
// B: lane holds B[8*(lane>>4)+e][lane&15]; D: D[4*(lane>>4)+r][lane&15]. (m89, R0-verified)
__device__ inline void mfma16x16x32bf16(f32x4& d, u32x4 a, u32x4 b) {
  asm volatile("v_mfma_f32_16x16x32_bf16 %0, %1, %2, %0" : "+v"(d) : "v"(a), "v"(b));
}

struct ProjArgs {
  const float* x[6];
  const float* w[6];
  const float* b[6];
  unsigned short* o[6];
  int mode[6];     // 0: out[n][64]   1: out[c][N]
  float scale[6];
};

// ---- 1x1x1 conv projections (unchanged from R2).
__global__ __launch_bounds__(256) void proj_kernel(ProjArgs A) {
  const int p = blockIdx.y;
  const float* __restrict__ x = A.x[p];
  const float* __restrict__ w = A.w[p];
  const float* __restrict__ bias = A.b[p];
  unsigned short* __restrict__ out = A.o[p];
  const int n0 = blockIdx.x * 128;
  __shared__ float Xs[64][128];
  __shared__ float Ws[64][64];
  const int t = threadIdx.x;
#pragma unroll
  for (int i = 0; i < 4; i++) {
    int s = t + i * 256;
    ((u32x4*)Ws)[s] = ((const u32x4*)w)[s];
  }
#pragma unroll
  for (int i = 0; i < 8; i++) {
    int s = t + i * 256;
    int c = s >> 5, nc = s & 31;
    *(u32x4*)&Xs[c][nc * 4] = *(const u32x4*)&x[c * N + n0 + nc * 4];
  }
  __syncthreads();
  const int n = t & 127, h = t >> 7;
  float acc[32];
#pragma unroll
  for (int o = 0; o < 32; o++) acc[o] = bias[h * 32 + o];
  for (int c = 0; c < 64; c++) {
    float xv = Xs[c][n];
#pragma unroll
    for (int o = 0; o < 32; o++) acc[o] = fmaf(Ws[h * 32 + o][c], xv, acc[o]);
  }
  const float sc = A.scale[p];
  if (A.mode[p] == 0) {
    unsigned short* po = out + (size_t)(n0 + n) * 64 + h * 32;
#pragma unroll
    for (int o = 0; o < 32; o++) po[o] = f2bf(acc[o] * sc);
  } else {
#pragma unroll
    for (int o = 0; o < 32; o++) out[(size_t)(h * 32 + o) * N + n0 + n] = f2bf(acc[o] * sc);
  }
}

// ---- flash cross-attention, barrier-free main loop, no-max softmax.
// All K/V fragments read directly from global (L2-resident); LDS only for the
// per-wave P tile. Block: 4 waves = {qsub 0..1} x {cw 0..1}; wave owns 32 Q rows
// x 1024-j chunk. P = exp2(S) with no running max (|S|<~1.3 for this data;
// exp2 range +-126 -> safe), so partials combine by plain summation.
__global__ __launch_bounds__(256, 3) void attn_kernel(
    const unsigned short* __restrict__ Q0, const unsigned short* __restrict__ K0,
    const unsigned short* __restrict__ V0, const unsigned short* __restrict__ Q1,
    const unsigned short* __restrict__ K1, const unsigned short* __restrict__ V1,
    unsigned short* __restrict__ Opart, float* __restrict__ Lsum) {
  const int dir = blockIdx.z;
  const unsigned short* __restrict__ Q = dir ? Q1 : Q0;
  const unsigned short* __restrict__ K = dir ? K1 : K0;
  const unsigned short* __restrict__ V = dir ? V1 : V0;
  const int qb = blockIdx.x;      // 128 tiles of 64 Q rows
  const int cpair = blockIdx.y;   // 0..3

  __shared__ char pbuf[16384];    // 4 waves x [32 q][64 j] bf16, XOR-swizzled
  __shared__ float mlb[64];       // 2 qsub x 32 q: partner-wave l

  const int t = threadIdx.x;
  const int lane = t & 63, w = t >> 6;
  const int qsub = w >> 1, cw = w & 1;
  const int kvbase = (cpair * 2 + cw) * 1024;
  const int g = lane >> 4, sl = lane & 15;
  char* const pw = pbuf + w * 4096;

  // Q^T B-fragments (held whole kernel)
  u32x4 qf[2][2];
#pragma unroll
  for (int rb = 0; rb < 2; rb++) {
    const int qrow = qb * 64 + qsub * 32 + rb * 16 + sl;
#pragma unroll
    for (int ks = 0; ks < 2; ks++)
      qf[rb][ks] = *(const u32x4*)(Q + (size_t)qrow * 64 + ks * 32 + 8 * g);
  }

  f32x4 acc[4][2];   // O^T[mb*16+4g+r][rb*16+sl]
#pragma unroll
  for (int mb = 0; mb < 4; mb++)
#pragma unroll
    for (int rb = 0; rb < 2; rb++)
#pragma unroll
      for (int r = 0; r < 4; r++) acc[mb][rb][r] = 0.f;
  float lpart[2] = {0.f, 0.f};

  for (int jt = 0; jt < 16; ++jt) {
    const int j0 = kvbase + jt * 64;
    // K A-fragments direct from global: K[(j0+jb*16+sl)][ks*32+8g ..+8]
    u32x4 kf[4][2];
#pragma unroll
    for (int jb = 0; jb < 4; jb++)
#pragma unroll
      for (int ks = 0; ks < 2; ks++)
        kf[jb][ks] = *(const u32x4*)(K + (size_t)(j0 + jb * 16 + sl) * 64 + ks * 32 + 8 * g);
    // V A-fragments direct from global: V[(mb*16+sl)][j0+ks*32+8g ..+8]
    u32x4 vf[4][2];
#pragma unroll
    for (int mb = 0; mb < 4; mb++)
#pragma unroll
      for (int ks = 0; ks < 2; ks++)
        vf[mb][ks] = *(const u32x4*)(V + (size_t)(mb * 16 + sl) * N + j0 + ks * 32 + 8 * g);

    // QK^T (swapped): st[jb][rb] = S^T[jb*16+4g+r][rb*16+sl]
    f32x4 st[4][2];
#pragma unroll
    for (int jb = 0; jb < 4; jb++)
#pragma unroll
      for (int rb = 0; rb < 2; rb++) {
#pragma unroll
        for (int r = 0; r < 4; r++) st[jb][rb][r] = 0.f;
        mfma16x16x32bf16(st[jb][rb], kf[jb][0], qf[rb][0]);
        mfma16x16x32bf16(st[jb][rb], kf[jb][1], qf[rb][1]);
      }

    // P = exp2(S) (no max subtraction), accumulate l, pack bf16, store to LDS
#pragma unroll
    for (int rb = 0; rb < 2; rb++) {
      const int q = rb * 16 + sl;
      const int qswz = (q & 7) << 4;
#pragma unroll
      for (int jb = 0; jb < 4; jb++) {
        float e0 = __builtin_amdgcn_exp2f(st[jb][rb][0]);
        float e1 = __builtin_amdgcn_exp2f(st[jb][rb][1]);
        float e2 = __builtin_amdgcn_exp2f(st[jb][rb][2]);
        float e3 = __builtin_amdgcn_exp2f(st[jb][rb][3]);
        lpart[rb] += (e0 + e1) + (e2 + e3);
        u32x2 pk;
        pk[0] = cvtpk(e0, e1);
        pk[1] = cvtpk(e2, e3);
        *(u32x2*)(pw + q * 128 + ((jb * 32 + 8 * g) ^ qswz)) = pk;
      }
    }

    // PV: O^T += V * P^T (P fragment read back from per-wave LDS tile)
    u32x4 pf[2][2];
#pragma unroll
    for (int rb = 0; rb < 2; rb++) {
      const int q = rb * 16 + sl;
      const int qswz = (q & 7) << 4;
      pf[rb][0] = *(const u32x4*)(pw + q * 128 + ((16 * g) ^ qswz));
      pf[rb][1] = *(const u32x4*)(pw + q * 128 + ((64 + 16 * g) ^ qswz));
    }
#pragma unroll
    for (int mb = 0; mb < 4; mb++)
#pragma unroll
      for (int rb = 0; rb < 2; rb++) {
        mfma16x16x32bf16(acc[mb][rb], vf[mb][0], pf[rb][0]);
        mfma16x16x32bf16(acc[mb][rb], vf[mb][1], pf[rb][1]);
      }
  }

  // full l per q: reduce across g-groups (lanes same sl)
#pragma unroll
  for (int rb = 0; rb < 2; rb++) {
    lpart[rb] += __shfl_xor(lpart[rb], 16);
    lpart[rb] += __shfl_xor(lpart[rb], 32);
  }

  // ---- in-block merge of the two cw partials (plain sums; overlay on pbuf)
  __syncthreads();
  char* const obuf = pbuf + qsub * 8192;    // [32 q][64 ch] f32, swizzled
  if (cw == 1) {
#pragma unroll
    for (int rb = 0; rb < 2; rb++) {
      const int q = rb * 16 + sl;
      const int qswz = (q & 7) << 4;
#pragma unroll
      for (int mb = 0; mb < 4; mb++)
        *(f32x4*)(obuf + q * 256 + (((mb * 16 + 4 * g) * 4) ^ qswz)) = acc[mb][rb];
      if (g == 0) mlb[qsub * 32 + q] = lpart[rb];
    }
  }
  __syncthreads();
  if (cw == 0) {
#pragma unroll
    for (int rb = 0; rb < 2; rb++) {
      const int q = rb * 16 + sl;
      const int qswz = (q & 7) << 4;
      const float ltot = lpart[rb] + mlb[qsub * 32 + q];
      const int qg = qb * 64 + qsub * 32 + q;
      const size_t pbase = ((size_t)(dir * SPLIT + cpair) * N + qg) * 64;
#pragma unroll
      for (int mb = 0; mb < 4; mb++) {
        f32x4 oo = *(const f32x4*)(obuf + q * 256 + (((mb * 16 + 4 * g) * 4) ^ qswz));
        u32x2 pk;
        pk[0] = cvtpk(acc[mb][rb][0] + oo[0], acc[mb][rb][1] + oo[1]);
        pk[1] = cvtpk(acc[mb][rb][2] + oo[2], acc[mb][rb][3] + oo[3]);
        *(u32x2*)(Opart + pbase + mb * 16 + 4 * g) = pk;
      }
      if (g == 0) Lsum[(size_t)(dir * SPLIT + cpair) * N + qg] = ltot;
    }
  }
}

// ---- combine the 4 chunk-pair partials (plain sums) -> fused[128][N] f32
__global__ __launch_bounds__(256) void merge_kernel(
    const unsigned short* __restrict__ Opart, const float* __restrict__ Lsum,
    float* __restrict__ fused) {
  const int t = threadIdx.x;
  const int dir = blockIdx.y;
  const int q = blockIdx.x * 64 + (t & 63);
  const int chg = t >> 6;   // 16 channels per thread
  float lt = 0.f;
#pragma unroll
  for (int c = 0; c < 4; c++) lt += Lsum[(size_t)(dir * SPLIT + c) * N + q];
  const float rD = 1.0f / lt;
  float o[16];
#pragma unroll
  for (int k = 0; k < 16; k++) o[k] = 0.f;
#pragma unroll
  for (int c = 0; c < 4; c++) {
    const u16x4* p = (const u16x4*)(Opart + ((size_t)(dir * SPLIT + c) * N + q) * 64 + chg * 16);
#pragma unroll
    for (int k4 = 0; k4 < 4; k4++) {
      u16x4 v = p[k4];
#pragma unroll
      for (int e4 = 0; e4 < 4; e4++) o[k4 * 4 + e4] += bf2f(v[e4]);
    }
  }
#pragma unroll
  for (int k = 0; k < 16; k++)
    fused[(size_t)(dir * 64 + chg * 16 + k) * N + q] = o[k] * rD;
}

// ---- output projection (unchanged from R2)
__global__ __launch_bounds__(256) void oproj_kernel(
    const float* __restrict__ fused, const float* __restrict__ wo,
    const float* __restrict__ bo, float* __restrict__ out) {
  __shared__ float Fs[128][64];
  __shared__ float Ws[64][128];
  const int t = threadIdx.x;
  const int n0 = blockIdx.x * 64;
#pragma unroll
  for (int i = 0; i < 8; i++) {
    int s = t + i * 256;
    ((u32x4*)Ws)[s] = ((const u32x4*)wo)[s];
  }
#pragma unroll
  for (int i = 0; i < 8; i++) {
    int s = t + i * 256;
    int ch = s >> 4, nc = s & 15;
    *(u32x4*)&Fs[ch][nc * 4] = *(const u32x4*)&fused[(size_t)ch * N + n0 + nc * 4];
  }
  __syncthreads();
  const int n = t & 63, h = t >> 6;
  float acc[16];
#pragma unroll
  for (int o = 0; o < 16; o++) acc[o] = bo[h * 16 + o];
  for (int ch = 0; ch < 128; ch++) {
    float fv = Fs[ch][n];
#pragma unroll
    for (int o = 0; o < 16; o++) acc[o] = fmaf(Ws[h * 16 + o][ch], fv, acc[o]);
  }
#pragma unroll
  for (int o = 0; o < 16; o++) out[(size_t)(h * 16 + o) * N + n0 + n] = acc[o];
}

extern "C" void kernel_launch(void* const* d_in, const int* in_sizes, int n_in,
                              void* d_out, int out_size, void* d_ws, size_t ws_size,
                              hipStream_t stream) {
  const float* ct     = (const float*)d_in[0];
  const float* mri    = (const float*)d_in[1];
  const float* wq_ct  = (const float*)d_in[2];
  const float* bq_ct  = (const float*)d_in[3];
  const float* wk_mri = (const float*)d_in[4];
  const float* bk_mri = (const float*)d_in[5];
  const float* wv_mri = (const float*)d_in[6];
  const float* bv_mri = (const float*)d_in[7];
  const float* wq_mri = (const float*)d_in[8];
  const float* bq_mri = (const float*)d_in[9];
  const float* wk_ct  = (const float*)d_in[10];
  const float* bk_ct  = (const float*)d_in[11];
  const float* wv_ct  = (const float*)d_in[12];
  const float* bv_ct  = (const float*)d_in[13];
  const float* wo     = (const float*)d_in[14];
  const float* bo     = (const float*)d_in[15];

  // ws layout (19 MB): [0,6M) 6x1MB bf16 projections; [6M,14M) Opart bf16
  // (2 dir x 4 chunkpair x 8192 x 64); [14M,14.5M) Lsum f32; [15M,19M) fused f32.
  char* ws = (char*)d_ws;
  const size_t MB = (size_t)1 << 20;
  unsigned short* Qt_ct  = (unsigned short*)(ws + 0 * MB);  // [n][64], pre-scaled
  unsigned short* Kt_mri = (unsigned short*)(ws + 1 * MB);  // [n][64]
  unsigned short* V_mri  = (unsigned short*)(ws + 2 * MB);  // [c][N]
  unsigned short* Qt_mri = (unsigned short*)(ws + 3 * MB);
  unsigned short* Kt_ct  = (unsigned short*)(ws + 4 * MB);
  unsigned short* V_ct   = (unsigned short*)(ws + 5 * MB);
  unsigned short* Opart  = (unsigned short*)(ws + 6 * MB);
  float* Lsum            = (float*)(ws + 14 * MB);
  float* fused           = (float*)(ws + 15 * MB);

  ProjArgs A;
  A.x[0] = ct;  A.w[0] = wq_ct;  A.b[0] = bq_ct;  A.o[0] = Qt_ct;  A.mode[0] = 0; A.scale[0] = QSCALE;
  A.x[1] = mri; A.w[1] = wk_mri; A.b[1] = bk_mri; A.o[1] = Kt_mri; A.mode[1] = 0; A.scale[1] = 1.f;
  A.x[2] = mri; A.w[2] = wv_mri; A.b[2] = bv_mri; A.o[2] = V_mri;  A.mode[2] = 1; A.scale[2] = 1.f;
  A.x[3] = mri; A.w[3] = wq_mri; A.b[3] = bq_mri; A.o[3] = Qt_mri; A.mode[3] = 0; A.scale[3] = QSCALE;
  A.x[4] = ct;  A.w[4] = wk_ct;  A.b[4] = bk_ct;  A.o[4] = Kt_ct;  A.mode[4] = 0; A.scale[4] = 1.f;
  A.x[5] = ct;  A.w[5] = wv_ct;  A.b[5] = bv_ct;  A.o[5] = V_ct;   A.mode[5] = 1; A.scale[5] = 1.f;

  proj_kernel<<<dim3(64, 6), 256, 0, stream>>>(A);
  attn_kernel<<<dim3(128, SPLIT, 2), 256, 0, stream>>>(Qt_ct, Kt_mri, V_mri,
                                                       Qt_mri, Kt_ct, V_ct, Opart, Lsum);
  merge_kernel<<<dim3(128, 2), 256, 0, stream>>>(Opart, Lsum, fused);
  oproj_kernel<<<dim3(128), 256, 0, stream>>>(fused, wo, bo, (float*)d_out);
}

// Round 5
// 157.172 us; speedup vs baseline: 1.0160x; 1.0160x over previous
//
#include <hip/hip_runtime.h>
#include <stdint.h>

// N = D*H*W = 8*32*32 voxels; C = 64 channels.
constexpr int N = 8192;
// softmax scale (1/sqrt(64)) * log2(e), folded into Q (attn works in exp2 domain).
constexpr float QSCALE = 0.18033688011112042f;
constexpr int SPLIT = 4;   // chunk-pairs; slice = dir*4+cpair pinned per-XCD

typedef __attribute__((ext_vector_type(4))) float f32x4;
typedef __attribute__((ext_vector_type(4))) unsigned int u32x4;
typedef __attribute__((ext_vector_type(2))) unsigned int u32x2;
typedef __attribute__((ext_vector_type(4))) unsigned short u16x4;

__device__ inline unsigned short f2bf(float f) {
  unsigned u = __builtin_bit_cast(unsigned, f);
  u += 0x7FFFu + ((u >> 16) & 1u);
  return (unsigned short)(u >> 16);
}
__device__ inline float bf2f(unsigned short u) {
  return __builtin_bit_cast(float, (unsigned)u << 16);
}
// pack two f32 -> two bf16 in one u32 (low=a, high=b)
__device__ inline unsigned cvtpk(float a, float b) {
  unsigned r;
  asm("v_cvt_pk_bf16_f32 %0, %1, %2" : "=v"(r) : "v"(a), "v"(b));
  return r;
}

// D = A*B + D, 16x16x32 bf16. A: lane holds A[lane&15][8*(lane>>4)+e];
// B: lane holds B[8*(lane>>4)+e][lane&15]; D: D[4*(lane>>4)+r][lane&15]. (m89)
// NOTE: inline-asm MFMA is invisible to the hazard recognizer -> consumers of D
// must sit well downstream (cluster-then-consume) + explicit s_nop guard below.
__device__ inline void mfma16x16x32bf16(f32x4& d, u32x4 a, u32x4 b) {
  asm volatile("v_mfma_f32_16x16x32_bf16 %0, %1, %2, %0" : "+v"(d) : "v"(a), "v"(b));
}
// pinned MFMA->VALU hazard guard: nothing may be scheduled across it.
__device__ inline void mfma_guard() {
  __builtin_amdgcn_sched_barrier(0);
  asm volatile("s_nop 7\n\ts_nop 7");
  __builtin_amdgcn_sched_barrier(0);
}

struct ProjArgs {
  const float* x[6];
  const float* w[6];
  const float* b[6];
  unsigned short* o[6];
  int mode[6];     // 0: out[n][64]   1: out[c][N]
  float scale[6];
};

// ---- 1x1x1 conv projections (unchanged).
__global__ __launch_bounds__(256) void proj_kernel(ProjArgs A) {
  const int p = blockIdx.y;
  const float* __restrict__ x = A.x[p];
  const float* __restrict__ w = A.w[p];
  const float* __restrict__ bias = A.b[p];
  unsigned short* __restrict__ out = A.o[p];
  const int n0 = blockIdx.x * 128;
  __shared__ float Xs[64][128];
  __shared__ float Ws[64][64];
  const int t = threadIdx.x;
#pragma unroll
  for (int i = 0; i < 4; i++) {
    int s = t + i * 256;
    ((u32x4*)Ws)[s] = ((const u32x4*)w)[s];
  }
#pragma unroll
  for (int i = 0; i < 8; i++) {
    int s = t + i * 256;
    int c = s >> 5, nc = s & 31;
    *(u32x4*)&Xs[c][nc * 4] = *(const u32x4*)&x[c * N + n0 + nc * 4];
  }
  __syncthreads();
  const int n = t & 127, h = t >> 7;
  float acc[32];
#pragma unroll
  for (int o = 0; o < 32; o++) acc[o] = bias[h * 32 + o];
  for (int c = 0; c < 64; c++) {
    float xv = Xs[c][n];
#pragma unroll
    for (int o = 0; o < 32; o++) acc[o] = fmaf(Ws[h * 32 + o][c], xv, acc[o]);
  }
  const float sc = A.scale[p];
  if (A.mode[p] == 0) {
    unsigned short* po = out + (size_t)(n0 + n) * 64 + h * 32;
#pragma unroll
    for (int o = 0; o < 32; o++) po[o] = f2bf(acc[o] * sc);
  } else {
#pragma unroll
    for (int o = 0; o < 32; o++) out[(size_t)(h * 32 + o) * N + n0 + n] = f2bf(acc[o] * sc);
  }
}

// ---- flash cross-attention, no-max softmax, XCD-sliced, R3-proven cluster order.
// Grid flat 1024: slice = bid&7 -> (dir, cpair); qb = bid>>3. All 128 qb-blocks of a
// slice co-reside on one XCD -> its K/V chunk (512 KB) + Q (1 MB) stay L2-hot.
// Block: 4 waves = {qsub} x {cw}; wave owns 32 Q rows x 1024-j chunk. Barrier-free
// main loop; per-wave P tile in LDS; P = exp2(S) (no running max; |S| small).
__global__ __launch_bounds__(256, 3) void attn_kernel(
    const unsigned short* __restrict__ Q0, const unsigned short* __restrict__ K0,
    const unsigned short* __restrict__ V0, const unsigned short* __restrict__ Q1,
    const unsigned short* __restrict__ K1, const unsigned short* __restrict__ V1,
    unsigned short* __restrict__ Opart, float* __restrict__ Lsum) {
  const int bid = blockIdx.x;
  const int slice = bid & 7;        // -> XCD (round-robin dispatch heuristic)
  const int qb = bid >> 3;          // 0..127
  const int dir = slice >> 2;
  const int cpair = slice & 3;
  const unsigned short* __restrict__ Q = dir ? Q1 : Q0;
  const unsigned short* __restrict__ K = dir ? K1 : K0;
  const unsigned short* __restrict__ V = dir ? V1 : V0;

  __shared__ char pbuf[16384];    // 4 waves x [32 q][64 j] bf16, XOR-swizzled
  __shared__ float mlb[64];

  const int t = threadIdx.x;
  const int lane = t & 63, w = t >> 6;
  const int qsub = w >> 1, cw = w & 1;
  const int kvbase = (cpair * 2 + cw) * 1024;
  const int g = lane >> 4, sl = lane & 15;
  char* const pw = pbuf + w * 4096;

  // Q^T B-fragments (held whole kernel)
  u32x4 qf[2][2];
#pragma unroll
  for (int rb = 0; rb < 2; rb++) {
    const int qrow = qb * 64 + qsub * 32 + rb * 16 + sl;
#pragma unroll
    for (int ks = 0; ks < 2; ks++)
      qf[rb][ks] = *(const u32x4*)(Q + (size_t)qrow * 64 + ks * 32 + 8 * g);
  }

  f32x4 acc[4][2];   // O^T[mb*16+4g+r][rb*16+sl]
#pragma unroll
  for (int mb = 0; mb < 4; mb++)
#pragma unroll
    for (int rb = 0; rb < 2; rb++)
#pragma unroll
      for (int r = 0; r < 4; r++) acc[mb][rb][r] = 0.f;
  float lpart[2] = {0.f, 0.f};

  for (int jt = 0; jt < 16; ++jt) {
    const int j0 = kvbase + jt * 64;
    // K A-fragments direct from global (L2-hot after slicing)
    u32x4 kf[4][2];
#pragma unroll
    for (int jb = 0; jb < 4; jb++)
#pragma unroll
      for (int ks = 0; ks < 2; ks++)
        kf[jb][ks] = *(const u32x4*)(K + (size_t)(j0 + jb * 16 + sl) * 64 + ks * 32 + 8 * g);
    // V A-fragments direct from global
    u32x4 vf[4][2];
#pragma unroll
    for (int mb = 0; mb < 4; mb++)
#pragma unroll
      for (int ks = 0; ks < 2; ks++)
        vf[mb][ks] = *(const u32x4*)(V + (size_t)(mb * 16 + sl) * N + j0 + ks * 32 + 8 * g);

    // QK^T cluster (swapped): st[jb][rb] = S^T[jb*16+4g+r][rb*16+sl]
    f32x4 st[4][2];
    __builtin_amdgcn_s_setprio(1);
#pragma unroll
    for (int jb = 0; jb < 4; jb++)
#pragma unroll
      for (int rb = 0; rb < 2; rb++) {
#pragma unroll
        for (int r = 0; r < 4; r++) st[jb][rb][r] = 0.f;
        mfma16x16x32bf16(st[jb][rb], kf[jb][0], qf[rb][0]);
        mfma16x16x32bf16(st[jb][rb], kf[jb][1], qf[rb][1]);
      }
    __builtin_amdgcn_s_setprio(0);
    mfma_guard();   // st written by asm MFMA; pin wait states before VALU reads

    // P = exp2(S), accumulate l, pack bf16, store to per-wave LDS tile
#pragma unroll
    for (int rb = 0; rb < 2; rb++) {
      const int q = rb * 16 + sl;
      const int qswz = (q & 7) << 4;
#pragma unroll
      for (int jb = 0; jb < 4; jb++) {
        float e0 = __builtin_amdgcn_exp2f(st[jb][rb][0]);
        float e1 = __builtin_amdgcn_exp2f(st[jb][rb][1]);
        float e2 = __builtin_amdgcn_exp2f(st[jb][rb][2]);
        float e3 = __builtin_amdgcn_exp2f(st[jb][rb][3]);
        lpart[rb] += (e0 + e1) + (e2 + e3);
        u32x2 pk;
        pk[0] = cvtpk(e0, e1);
        pk[1] = cvtpk(e2, e3);
        *(u32x2*)(pw + q * 128 + ((jb * 32 + 8 * g) ^ qswz)) = pk;
      }
    }

    // PV cluster: O^T += V * P^T (P fragment read back from per-wave LDS tile)
    u32x4 pf[2][2];
#pragma unroll
    for (int rb = 0; rb < 2; rb++) {
      const int q = rb * 16 + sl;
      const int qswz = (q & 7) << 4;
      pf[rb][0] = *(const u32x4*)(pw + q * 128 + ((16 * g) ^ qswz));
      pf[rb][1] = *(const u32x4*)(pw + q * 128 + ((64 + 16 * g) ^ qswz));
    }
    __builtin_amdgcn_s_setprio(1);
#pragma unroll
    for (int mb = 0; mb < 4; mb++)
#pragma unroll
      for (int rb = 0; rb < 2; rb++) {
        mfma16x16x32bf16(acc[mb][rb], vf[mb][0], pf[rb][0]);
        mfma16x16x32bf16(acc[mb][rb], vf[mb][1], pf[rb][1]);
      }
    __builtin_amdgcn_s_setprio(0);
  }
  mfma_guard();   // acc read below (merge) — pin hazard distance

  // full l per q: reduce across g-groups
#pragma unroll
  for (int rb = 0; rb < 2; rb++) {
    lpart[rb] += __shfl_xor(lpart[rb], 16);
    lpart[rb] += __shfl_xor(lpart[rb], 32);
  }

  // ---- in-block merge of the two cw partials (plain sums; overlay on pbuf)
  __syncthreads();
  char* const obuf = pbuf + qsub * 8192;    // [32 q][64 ch] f32, swizzled
  if (cw == 1) {
#pragma unroll
    for (int rb = 0; rb < 2; rb++) {
      const int q = rb * 16 + sl;
      const int qswz = (q & 7) << 4;
#pragma unroll
      for (int mb = 0; mb < 4; mb++)
        *(f32x4*)(obuf + q * 256 + (((mb * 16 + 4 * g) * 4) ^ qswz)) = acc[mb][rb];
      if (g == 0) mlb[qsub * 32 + q] = lpart[rb];
    }
  }
  __syncthreads();
  if (cw == 0) {
#pragma unroll
    for (int rb = 0; rb < 2; rb++) {
      const int q = rb * 16 + sl;
      const int qswz = (q & 7) << 4;
      const float ltot = lpart[rb] + mlb[qsub * 32 + q];
      const int qg = qb * 64 + qsub * 32 + q;
      const size_t pbase = ((size_t)(dir * SPLIT + cpair) * N + qg) * 64;
#pragma unroll
      for (int mb = 0; mb < 4; mb++) {
        f32x4 oo = *(const f32x4*)(obuf + q * 256 + (((mb * 16 + 4 * g) * 4) ^ qswz));
        u32x2 pk;
        pk[0] = cvtpk(acc[mb][rb][0] + oo[0], acc[mb][rb][1] + oo[1]);
        pk[1] = cvtpk(acc[mb][rb][2] + oo[2], acc[mb][rb][3] + oo[3]);
        *(u32x2*)(Opart + pbase + mb * 16 + 4 * g) = pk;
      }
      if (g == 0) Lsum[(size_t)(dir * SPLIT + cpair) * N + qg] = ltot;
    }
  }
}

// ---- fused merge + output projection:
// Fs[dir*64+ch][q] = (sum_c Opart[slice][q][ch]) / (sum_c Lsum[slice][q]); then GEMM with wo.
__global__ __launch_bounds__(256) void oproj_kernel(
    const unsigned short* __restrict__ Opart, const float* __restrict__ Lsum,
    const float* __restrict__ wo, const float* __restrict__ bo,
    float* __restrict__ out) {
  __shared__ float Fs[128][64];   // 32 KB
  __shared__ float Ws[64][128];   // 32 KB
  const int t = threadIdx.x;
  const int n0 = blockIdx.x * 64;
#pragma unroll
  for (int i = 0; i < 8; i++) {
    int s = t + i * 256;
    ((u32x4*)Ws)[s] = ((const u32x4*)wo)[s];
  }
  const int q = t & 63;     // local voxel (lane)
  const int cg = t >> 6;    // wave: 4 ch4-groups each
#pragma unroll
  for (int dir = 0; dir < 2; dir++) {
    float lt = 0.f;
#pragma unroll
    for (int c = 0; c < 4; c++) lt += Lsum[(size_t)(dir * SPLIT + c) * N + n0 + q];
    const float rD = 1.0f / lt;
#pragma unroll
    for (int i = 0; i < 4; i++) {
      const int ch4 = cg * 4 + i;   // channels ch4*4 .. +4
      float s0 = 0.f, s1 = 0.f, s2 = 0.f, s3 = 0.f;
#pragma unroll
      for (int c = 0; c < 4; c++) {
        u16x4 v = *(const u16x4*)(Opart +
            ((size_t)(dir * SPLIT + c) * N + n0 + q) * 64 + ch4 * 4);
        s0 += bf2f(v[0]); s1 += bf2f(v[1]); s2 += bf2f(v[2]); s3 += bf2f(v[3]);
      }
      Fs[dir * 64 + ch4 * 4 + 0][q] = s0 * rD;
      Fs[dir * 64 + ch4 * 4 + 1][q] = s1 * rD;
      Fs[dir * 64 + ch4 * 4 + 2][q] = s2 * rD;
      Fs[dir * 64 + ch4 * 4 + 3][q] = s3 * rD;
    }
  }
  __syncthreads();
  const int n = t & 63, h = t >> 6;
  float acc[16];
#pragma unroll
  for (int o = 0; o < 16; o++) acc[o] = bo[h * 16 + o];
  for (int ch = 0; ch < 128; ch++) {
    float fv = Fs[ch][n];
#pragma unroll
    for (int o = 0; o < 16; o++) acc[o] = fmaf(Ws[h * 16 + o][ch], fv, acc[o]);
  }
#pragma unroll
  for (int o = 0; o < 16; o++) out[(size_t)(h * 16 + o) * N + n0 + n] = acc[o];
}

extern "C" void kernel_launch(void* const* d_in, const int* in_sizes, int n_in,
                              void* d_out, int out_size, void* d_ws, size_t ws_size,
                              hipStream_t stream) {
  const float* ct     = (const float*)d_in[0];
  const float* mri    = (const float*)d_in[1];
  const float* wq_ct  = (const float*)d_in[2];
  const float* bq_ct  = (const float*)d_in[3];
  const float* wk_mri = (const float*)d_in[4];
  const float* bk_mri = (const float*)d_in[5];
  const float* wv_mri = (const float*)d_in[6];
  const float* bv_mri = (const float*)d_in[7];
  const float* wq_mri = (const float*)d_in[8];
  const float* bq_mri = (const float*)d_in[9];
  const float* wk_ct  = (const float*)d_in[10];
  const float* bk_ct  = (const float*)d_in[11];
  const float* wv_ct  = (const float*)d_in[12];
  const float* bv_ct  = (const float*)d_in[13];
  const float* wo     = (const float*)d_in[14];
  const float* bo     = (const float*)d_in[15];

  // ws layout: [0,6M) 6x1MB bf16 projections; [6M,14M) Opart bf16; [14M,14.5M) Lsum f32.
  char* ws = (char*)d_ws;
  const size_t MB = (size_t)1 << 20;
  unsigned short* Qt_ct  = (unsigned short*)(ws + 0 * MB);  // [n][64], pre-scaled
  unsigned short* Kt_mri = (unsigned short*)(ws + 1 * MB);  // [n][64]
  unsigned short* V_mri  = (unsigned short*)(ws + 2 * MB);  // [c][N]
  unsigned short* Qt_mri = (unsigned short*)(ws + 3 * MB);
  unsigned short* Kt_ct  = (unsigned short*)(ws + 4 * MB);
  unsigned short* V_ct   = (unsigned short*)(ws + 5 * MB);
  unsigned short* Opart  = (unsigned short*)(ws + 6 * MB);
  float* Lsum            = (float*)(ws + 14 * MB);

  ProjArgs A;
  A.x[0] = ct;  A.w[0] = wq_ct;  A.b[0] = bq_ct;  A.o[0] = Qt_ct;  A.mode[0] = 0; A.scale[0] = QSCALE;
  A.x[1] = mri; A.w[1] = wk_mri; A.b[1] = bk_mri; A.o[1] = Kt_mri; A.mode[1] = 0; A.scale[1] = 1.f;
  A.x[2] = mri; A.w[2] = wv_mri; A.b[2] = bv_mri; A.o[2] = V_mri;  A.mode[2] = 1; A.scale[2] = 1.f;
  A.x[3] = mri; A.w[3] = wq_mri; A.b[3] = bq_mri; A.o[3] = Qt_mri; A.mode[3] = 0; A.scale[3] = QSCALE;
  A.x[4] = ct;  A.w[4] = wk_ct;  A.b[4] = bk_ct;  A.o[4] = Kt_ct;  A.mode[4] = 0; A.scale[4] = 1.f;
  A.x[5] = ct;  A.w[5] = wv_ct;  A.b[5] = bv_ct;  A.o[5] = V_ct;   A.mode[5] = 1; A.scale[5] = 1.f;

  proj_kernel<<<dim3(64, 6), 256, 0, stream>>>(A);
  attn_kernel<<<dim3(1024), 256, 0, stream>>>(Qt_ct, Kt_mri, V_mri,
                                              Qt_mri, Kt_ct, V_ct, Opart, Lsum);
  oproj_kernel<<<dim3(128), 256, 0, stream>>>(Opart, Lsum, wo, bo, (float*)d_out);
}